// Round 5
// baseline (92.552 us; speedup 1.0000x reference)
//
#include <hip/hip_runtime.h>

#define NMAX   64
#define NSITES 12
#define SPLIT  4      // threads per batch element (3 sites each)
#define BLOCK  256
#define RS     68     // LDS row stride (floats): rows 16B-aligned; site bank
                      // bases 4*{0,12,24,36}%32 = {0,12,24,4} -> the four
                      // b128 spans per wave-read hit disjoint banks

#define LOG2E  1.44269504088896340736f
#define LN2    0.69314718055994530942f
#define B_SOFT 0.01f
#define PAD_C  4.0e4f  // scaled sentinel: rp~5.66e4 -> 2^-rp==0 exactly;
                       // d~3.92e4 -> d^4 ~ 2.4e18 stays in f32 range

// deg-4 Taylor of 2^g on [-1/2, 1/2] (rel err ~4e-5, plenty vs threshold)
#define A1 0.69314718056f
#define A2 0.24022650700f
#define A3 0.05550410866f
#define A4 0.00961812911f

typedef float v2f __attribute__((ext_vector_type(2)));

__global__ __launch_bounds__(BLOCK, 8)
void pot_energy_kernel(const float* __restrict__ x,
                       const float* __restrict__ neighbors,
                       const float* __restrict__ mask,
                       float* __restrict__ out, int B) {
    __shared__ float nbx[NSITES][RS];   // log2e-scaled neighbor x
    __shared__ float nby[NSITES][RS];   // log2e-scaled neighbor y
    __shared__ int   cnt[NSITES];

    const int tid  = threadIdx.x;
    const int wv   = tid >> 6;
    const int lane = tid & 63;

    // Sentinel fill (iterations past a site's count contribute exactly 0).
    for (int idx = tid; idx < NSITES * RS; idx += BLOCK) {
        const int s = idx / RS, j = idx - s * RS;
        nbx[s][j] = PAD_C;
        nby[s][j] = PAD_C;
    }
    __syncthreads();

    // Ballot-compaction of neighbor lists into SoA LDS (~64 -> ~58).
    for (int s = wv; s < NSITES; s += 4) {
        const bool keep = mask[s * NMAX + lane] > 0.5f;
        const unsigned long long bal = __ballot(keep);
        if (keep) {
            const int pos = __popcll(bal & ((1ull << lane) - 1ull));
            const float2 p = ((const float2*)neighbors)[s * NMAX + lane];
            nbx[s][pos] = p.x * LOG2E;
            nby[s][pos] = p.y * LOG2E;
        }
        if (lane == 0) cnt[s] = __popcll(bal);
    }
    __syncthreads();

    // Uniform loop bound: max over all sites (identical in every lane).
    int m = 0;
    #pragma unroll
    for (int s = 0; s < NSITES; ++s) m = max(m, cnt[s]);
    m = (__builtin_amdgcn_readfirstlane(m) + 3) & ~3;   // <= 64

    const int gtid = blockIdx.x * BLOCK + tid;
    const int e = gtid >> 2;
    const int q = gtid & 3;
    if (e >= B) return;

    const float2* xp = (const float2*)(x + (size_t)gtid * 6);
    const float2 p0 = xp[0], p1 = xp[1], p2 = xp[2];
    const float xs_[3] = { p0.x * LOG2E, p1.x * LOG2E, p2.x * LOG2E };
    const float ys_[3] = { p0.y * LOG2E, p1.y * LOG2E, p2.y * LOG2E };

    float acc = 0.f;
    #pragma unroll
    for (int s = 0; s < 3; ++s) {
        const int site = q * 3 + s;
        const v2f xs2 = { xs_[s], xs_[s] };
        const v2f ys2 = { ys_[s], ys_[s] };
        const float* __restrict__ rx = nbx[site];
        const float* __restrict__ ry = nby[site];
        for (int j0 = 0; j0 < m; j0 += 4) {
            const float4 nx4 = *(const float4*)(rx + j0);
            const float4 ny4 = *(const float4*)(ry + j0);
            const v2f nxa = { nx4.x, nx4.y }, nxb = { nx4.z, nx4.w };
            const v2f nya = { ny4.x, ny4.y }, nyb = { ny4.z, ny4.w };

            // quadratic part, packed (v_pk_sub/mul/fma)
            const v2f dxa = xs2 - nxa, dxb = xs2 - nxb;
            const v2f dya = ys2 - nya, dyb = ys2 - nyb;
            const v2f r2a = dya * dya + dxa * dxa;   // (log2e*r)^2 pairs
            const v2f r2b = dyb * dyb + dxb * dxb;

            v2f rpa, rpb;                            // log2e * r
            rpa.x = __builtin_amdgcn_sqrtf(r2a.x);
            rpa.y = __builtin_amdgcn_sqrtf(r2a.y);
            rpb.x = __builtin_amdgcn_sqrtf(r2b.x);
            rpb.y = __builtin_amdgcn_sqrtf(r2b.y);

            // denominators r + b, packed
            const v2f da = rpa * LN2 + B_SOFT;
            const v2f db = rpb * LN2 + B_SOFT;

            // exp(-r) = 2^(-rp) via rint split + deg-4 poly + ldexp (VALU)
            v2f fma_, fmb_;
            fma_.x = __builtin_rintf(rpa.x);
            fma_.y = __builtin_rintf(rpa.y);
            fmb_.x = __builtin_rintf(rpb.x);
            fmb_.y = __builtin_rintf(rpb.y);
            const v2f ga = fma_ - rpa;               // in [-1/2, 1/2]
            const v2f gb = fmb_ - rpb;
            v2f ha = ((A4 * ga + A3) * ga + A2) * ga + A1;
            ha = ha * ga + 1.0f;                     // 2^ga
            v2f hb = ((A4 * gb + A3) * gb + A2) * gb + A1;
            hb = hb * gb + 1.0f;
            const float ex0 = __builtin_ldexpf(ha.x, (int)(-fma_.x));
            const float ex1 = __builtin_ldexpf(ha.y, (int)(-fma_.y));
            const float ex2 = __builtin_ldexpf(hb.x, (int)(-fmb_.x));
            const float ex3 = __builtin_ldexpf(hb.y, (int)(-fmb_.y));

            // pair-division merge: one rcp per 4 interactions
            const float d0 = da.x, d1 = da.y, d2 = db.x, d3 = db.y;
            const float p01 = d0 * d1;
            const float p23 = d2 * d3;
            const float n01 = fmaf(ex1, d0, ex0 * d1);
            const float n23 = fmaf(ex3, d2, ex2 * d3);
            const float den = p01 * p23;
            const float R   = __builtin_amdgcn_rcpf(den);
            const float N   = fmaf(n23, p01, n01 * p23);
            acc = fmaf(N, R, acc);
        }
    }

    acc += __shfl_xor(acc, 1);   // combine the 4 partials of element e
    acc += __shfl_xor(acc, 2);
    if (q == 0) out[e] = acc;
}

extern "C" void kernel_launch(void* const* d_in, const int* in_sizes, int n_in,
                              void* d_out, int out_size, void* d_ws, size_t ws_size,
                              hipStream_t stream) {
    const float* x   = (const float*)d_in[0];
    const float* nbr = (const float*)d_in[1];
    const float* msk = (const float*)d_in[2];
    float* out = (float*)d_out;

    const int B = in_sizes[0] / 24;
    const int total_threads = B * SPLIT;
    const int blocks = (total_threads + BLOCK - 1) / BLOCK;
    pot_energy_kernel<<<blocks, BLOCK, 0, stream>>>(x, nbr, msk, out, B);
}

// Round 6
// 83.392 us; speedup vs baseline: 1.1098x; 1.1098x over previous
//
#include <hip/hip_runtime.h>

#define NMAX   64
#define NSITES 12
#define SPLIT  4      // threads per batch element (3 sites each)
#define BLOCK  256
#define RS     68     // LDS row stride (floats): rows 16B-aligned; the 4
                      // site rows read per wave-op start at banks
                      // {0,12,24,4} -> disjoint b128 spans, conflict-free

#define B_SOFT 0.01f
#define PAD_C  4.0e4f   // sentinel coord -> r2 ~ 3e9 -> clamped -> f ~ 1e-8
#define R2_MAX 248.0f   // top of table range (bits 0x43780000 -> last bin)
#define TBL_LO 1392     // (bits >> 19) of 2^-40
#define TBL_N  768      // bins 1392..2159, 16 per octave, 48 octaves

// f(r2) = exp(-sqrt(r2)) / (sqrt(r2) + b), exact (device libm, build only)
__device__ __forceinline__ float f_exact(float r2) {
    const float r = sqrtf(r2);
    return expf(-r) / (r + B_SOFT);
}

__global__ __launch_bounds__(BLOCK, 8)
void pot_energy_kernel(const float* __restrict__ x,
                       const float* __restrict__ neighbors,
                       const float* __restrict__ mask,
                       float* __restrict__ out, int B) {
    __shared__ float  nbx[NSITES][RS];
    __shared__ float  nby[NSITES][RS];
    __shared__ float2 tbl[TBL_N];     // (c, s): f ~= c + s*r2 within the bin
    __shared__ int    cnt[NSITES];

    const int tid  = threadIdx.x;
    const int wv   = tid >> 6;
    const int lane = tid & 63;

    // Build the piecewise-linear table (once per block; 3 entries/thread).
    // Bin i covers r2 in [bitcast((i+LO)<<19), bitcast((i+LO+1)<<19)).
    for (int i = tid; i < TBL_N; i += BLOCK) {
        const unsigned ii = (unsigned)(i + TBL_LO);
        const float b0 = __builtin_bit_cast(float, ii << 19);
        const float b1 = __builtin_bit_cast(float, (ii + 1u) << 19);
        const float f0 = f_exact(b0);
        const float f1 = f_exact(b1);
        const float fm = f_exact(0.5f * (b0 + b1));
        const float s  = (f1 - f0) / (b1 - b0);
        // chord with midpoint correction (halves the max lerp error)
        const float c  = f0 - s * b0 - 0.5f * (0.5f * (f0 + f1) - fm);
        tbl[i] = make_float2(c, s);
    }

    // Sentinel fill: iterations past a site's compacted count give r2~3e9
    // -> clamped to last bin -> contribute ~1e-8 each (negligible).
    for (int idx = tid; idx < NSITES * RS; idx += BLOCK) {
        const int s = idx / RS, j = idx - s * RS;
        nbx[s][j] = PAD_C;
        nby[s][j] = PAD_C;
    }
    __syncthreads();

    // Ballot-compaction of neighbor lists into SoA LDS (~64 -> ~58).
    for (int s = wv; s < NSITES; s += 4) {
        const bool keep = mask[s * NMAX + lane] > 0.5f;
        const unsigned long long bal = __ballot(keep);
        if (keep) {
            const int pos = __popcll(bal & ((1ull << lane) - 1ull));
            const float2 p = ((const float2*)neighbors)[s * NMAX + lane];
            nbx[s][pos] = p.x;
            nby[s][pos] = p.y;
        }
        if (lane == 0) cnt[s] = __popcll(bal);
    }
    __syncthreads();

    // Uniform loop bound: max count over all sites (identical in every lane).
    int m = 0;
    #pragma unroll
    for (int s = 0; s < NSITES; ++s) m = max(m, cnt[s]);
    m = (__builtin_amdgcn_readfirstlane(m) + 3) & ~3;   // <= 64, RS-safe

    const int gtid = blockIdx.x * BLOCK + tid;
    const int e = gtid >> 2;
    const int q = gtid & 3;
    if (e >= B) return;

    const float2* xp = (const float2*)(x + (size_t)gtid * 6);
    const float2 p0 = xp[0], p1 = xp[1], p2 = xp[2];
    const float xs_[3] = { p0.x, p1.x, p2.x };
    const float ys_[3] = { p0.y, p1.y, p2.y };

    float accC = 0.f, accS = 0.f;   // sum(c_i) and sum(s_i * r2_i)
    #pragma unroll
    for (int s = 0; s < 3; ++s) {
        const int site = q * 3 + s;
        const float xs = xs_[s];
        const float ys = ys_[s];
        const float* __restrict__ rx = nbx[site];
        const float* __restrict__ ry = nby[site];
        #pragma unroll 2
        for (int j0 = 0; j0 < m; j0 += 4) {
            const float4 nx4 = *(const float4*)(rx + j0);
            const float4 ny4 = *(const float4*)(ry + j0);
            const float nx[4] = { nx4.x, nx4.y, nx4.z, nx4.w };
            const float ny[4] = { ny4.x, ny4.y, ny4.z, ny4.w };
            #pragma unroll
            for (int k = 0; k < 4; ++k) {
                const float dx = xs - nx[k];
                const float dy = ys - ny[k];
                float r2 = fmaf(dy, dy, dx * dx);
                r2 = fminf(r2, R2_MAX);             // also catches sentinels
                const unsigned bits = __builtin_bit_cast(unsigned, r2);
                int idx = (int)(bits >> 19) - TBL_LO;
                idx = idx < 0 ? 0 : idx;            // tiny r2 -> first bin
                const float2 cs = tbl[idx];         // ds_read_b64 (random)
                accC += cs.x;
                accS = fmaf(cs.y, r2, accS);
            }
        }
    }

    float acc = accC + accS;
    acc += __shfl_xor(acc, 1);   // combine the 4 partials of element e
    acc += __shfl_xor(acc, 2);
    if (q == 0) out[e] = acc;
}

extern "C" void kernel_launch(void* const* d_in, const int* in_sizes, int n_in,
                              void* d_out, int out_size, void* d_ws, size_t ws_size,
                              hipStream_t stream) {
    const float* x   = (const float*)d_in[0];
    const float* nbr = (const float*)d_in[1];
    const float* msk = (const float*)d_in[2];
    float* out = (float*)d_out;

    const int B = in_sizes[0] / 24;
    const int total_threads = B * SPLIT;
    const int blocks = (total_threads + BLOCK - 1) / BLOCK;
    pot_energy_kernel<<<blocks, BLOCK, 0, stream>>>(x, nbr, msk, out, B);
}